// Round 3
// baseline (97.052 us; speedup 1.0000x reference)
//
#include <hip/hip_runtime.h>
#include <hip/hip_bf16.h>

typedef __attribute__((ext_vector_type(8))) short short8;
typedef __attribute__((ext_vector_type(4))) float f32x4;
typedef __attribute__((ext_vector_type(16))) float f32x16;

#define B_  32
#define CH  256
#define S_  1024
#define NH  8
#define HD  32

static __device__ __forceinline__ unsigned short f2bf(float f) {
  __hip_bfloat16 h = __float2bfloat16(f);
  return *reinterpret_cast<unsigned short*>(&h);
}

// Async global->LDS DMA, 16B per lane. LDS dest = wave-uniform base + lane*16.
static __device__ __forceinline__ void gl_lds16(const void* g, void* l) {
  __builtin_amdgcn_global_load_lds(
      (const __attribute__((address_space(1))) void*)g,
      (__attribute__((address_space(3))) void*)l, 16, 0, 0);
}

// ---------------- Kernel 1: prep = xpose (blocks 0..8191) + wconv (8192..) ---
// xpose: x (B,C,S) fp32 -> xt (B,S,C) bf16 via 32x32 LDS tile.
// wconv: fold (1/sqrt(32))*log2(e) into Q weights+bias, convert to bf16;
// scores then live in the log2 domain -> softmax exp is a bare v_exp_f32.
__global__ void k_prep(const float* __restrict__ x, unsigned short* __restrict__ xt,
                       const float* __restrict__ qw, const float* __restrict__ qb,
                       const float* __restrict__ kvw, const float* __restrict__ kvb,
                       unsigned short* __restrict__ wt, float* __restrict__ bias) {
  __shared__ float tile[32][33];
  int blk = (int)blockIdx.x;
  int t = threadIdx.x;
  if (blk < 8192) {                                   // ---- xpose ----
    int b = blk >> 8;
    int inner = blk & 255;
    int ct = inner >> 5, st = inner & 31;             // 8 c-tiles x 32 s-tiles
    int c0 = ct * 32, s0 = st * 32;
    int r = t >> 3, q4 = (t & 7) * 4;
    const float4 v = *reinterpret_cast<const float4*>(
        x + ((size_t)(b * CH + c0 + r)) * S_ + s0 + q4);
    tile[r][q4 + 0] = v.x; tile[r][q4 + 1] = v.y;
    tile[r][q4 + 2] = v.z; tile[r][q4 + 3] = v.w;
    __syncthreads();
    ushort4 u;
    u.x = f2bf(tile[q4 + 0][r]); u.y = f2bf(tile[q4 + 1][r]);
    u.z = f2bf(tile[q4 + 2][r]); u.w = f2bf(tile[q4 + 3][r]);
    *reinterpret_cast<ushort4*>(xt + ((size_t)(b * S_ + s0 + r)) * CH + c0 + q4) = u;
  } else {                                            // ---- wconv ----
    int gid = (blk - 8192) * 256 + t;                 // 0..196607
    const float rs = 0.25503531838951954f;            // log2(e)/sqrt(32)
    int o = gid >> 8, c = gid & 255;
    float v = (o < 256) ? qw[o * 256 + c] * rs : kvw[(o - 256) * 256 + c];
    wt[gid] = f2bf(v);
    if (gid < 768) bias[gid] = (gid < 256) ? qb[gid] * rs : kvb[gid - 256];
  }
}

// ---------------- Kernel 2: projection GEMM (768x1024x256 per batch) ---------
// R20: LDS-FREE. R19's lesson: zero bank conflicts + counted-vmcnt pipeline
// still lost 6us because the kb-plane-major DMA source scattered each
// global_load_lds over 64 distinct cache lines (4x transaction rate). Root
// issue: the LDS-staging path itself (linear-dest DMA constraint + barriers)
// is the bottleneck structure for this tiny K=256 GEMM whose operands are
// L2-resident anyway (FETCH 10.5MB vs ~200MB logical reads = ~95% L2 hit).
// So: load MFMA fragments DIRECTLY from global. Each fragment quad is a
// global_load_dwordx4 where lanes (lr,rb) cover 16 full 64B lines (1KB,
// perfectly coalesced). No barriers -> no lock-step; register double-buffer
// (P/Q) gives explicit depth-1 prefetch; VGPR ~150 -> 3 waves/SIMD.
// Per-wave redundancy (2x A, 2x B per block) lands on L2 (~34 TB/s).
// K and V written in the PLANE-MAJOR PER-TILE layout k_attn stages:
//   kv[bh][t][0..1023]   : K-tile - plane p (dims 8p..8p+7) x 32 keys x 8
//   kv[bh][t][1024..2047]: V-tile - plane s (sigma-keys 8s..8s+7) x 32 dims x 8
// sigma = swap bits 2<->3 of the local key index (PV B-fragment order).

#define LDF(P, step) do {                                           \
    _Pragma("unroll")                                               \
    for (int mf = 0; mf < 4; ++mf)                                  \
      P##a[mf] = *reinterpret_cast<const short8*>(                  \
          wA + mf * 16 * CH + (step) * 32);                         \
    _Pragma("unroll")                                               \
    for (int nf = 0; nf < 4; ++nf)                                  \
      P##b[nf] = *reinterpret_cast<const short8*>(                  \
          xB + nf * 16 * CH + (step) * 32);                         \
  } while (0)

#define CMP(P) do {                                                 \
    _Pragma("unroll")                                               \
    for (int mf = 0; mf < 4; ++mf)                                  \
      _Pragma("unroll")                                             \
      for (int nf = 0; nf < 4; ++nf)                                \
        acc[mf][nf] = __builtin_amdgcn_mfma_f32_16x16x32_bf16(      \
            P##a[mf], P##b[nf], acc[mf][nf], 0, 0, 0);              \
  } while (0)

__global__ __launch_bounds__(256) void k_proj(
    const unsigned short* __restrict__ wt, const float* __restrict__ bias,
    const unsigned short* __restrict__ xt,
    unsigned short* __restrict__ qws, unsigned short* __restrict__ kv) {
  int b = blockIdx.y;
  int mt = blockIdx.x >> 3, nt = blockIdx.x & 7;      // 6 m-tiles x 8 n-tiles
  int tid = threadIdx.x;
  int wid = tid >> 6, l = tid & 63;
  int rb = l >> 4, lr = l & 15;                       // k-chunk, row-in-16
  int wr = wid >> 1, wc = wid & 1;
  int mb = mt * 128, nb = nt * 128;                   // block tile bases
  int wm = wr * 64, wn = wc * 64;                     // wave offsets in tile

  // Per-lane fragment bases: lane (lr, rb) of fragment (mf/nf) reads 16B at
  // row = base + frag*16 + lr, cols k = step*32 + rb*8. One dwordx4 per
  // fragment = 16 lanes x 4 k-chunks = 16 full 64B lines, coalesced.
  const unsigned short* wA = wt + (size_t)(mb + wm + lr) * CH + rb * 8;
  const unsigned short* xB = xt + (size_t)b * S_ * CH
                           + (size_t)(nb + wn + lr) * CH + rb * 8;

  f32x4 acc[4][4];
  #pragma unroll
  for (int mf = 0; mf < 4; ++mf)
    #pragma unroll
    for (int nf = 0; nf < 4; ++nf)
      acc[mf][nf] = (f32x4){0.f, 0.f, 0.f, 0.f};

  short8 Pa[4], Pb[4], Qa[4], Qb[4];                  // double-buffered frags

  LDF(P, 0); LDF(Q, 1);                               // prologue: 16 loads
  CMP(P); LDF(P, 2);                                  // step 0, prefetch 2
  CMP(Q); LDF(Q, 3);                                  // step 1, prefetch 3
  CMP(P); LDF(P, 4);                                  // step 2, prefetch 4
  CMP(Q); LDF(Q, 5);                                  // step 3, prefetch 5
  CMP(P); LDF(P, 6);                                  // step 4, prefetch 6
  CMP(Q); LDF(Q, 7);                                  // step 5, prefetch 7
  CMP(P);                                             // step 6
  CMP(Q);                                             // step 7

  #pragma unroll
  for (int mf = 0; mf < 4; ++mf) {
    int m0 = mb + wm + mf * 16 + rb * 4;
    const float4 bv = *reinterpret_cast<const float4*>(bias + m0);
    #pragma unroll
    for (int nf = 0; nf < 4; ++nf) {
      int n = nb + wn + nf * 16 + lr;                 // spatial s (key index)
      float v0 = acc[mf][nf][0] + bv.x;
      float v1 = acc[mf][nf][1] + bv.y;
      float v2 = acc[mf][nf][2] + bv.z;
      float v3 = acc[mf][nf][3] + bv.w;
      if (m0 < 256) {
        int h = m0 >> 5, d = m0 & 31;
        ushort4 u = {f2bf(v0), f2bf(v1), f2bf(v2), f2bf(v3)};
        *reinterpret_cast<ushort4*>(
            qws + ((size_t)(b * NH + h) * S_ + n) * HD + d) = u;
      } else if (m0 < 512) {
        int mm = m0 - 256; int h = mm >> 5, d0 = mm & 31;   // dims d0..d0+3
        size_t off = (((size_t)(b * NH + h) * 32 + (n >> 5)) * 2048)
                   + (size_t)((d0 >> 3) * 256 + (n & 31) * 8 + (d0 & 7));
        ushort4 u = {f2bf(v0), f2bf(v1), f2bf(v2), f2bf(v3)};
        *reinterpret_cast<ushort4*>(kv + off) = u;          // same plane: 8B store
      } else {
        int mm = m0 - 512; int h = mm >> 5, d0 = mm & 31;   // dims d0..d0+3
        int nl = n & 31;                                    // sigma: swap bits 2,3
        int kp = (nl & 19) | (((nl >> 2) & 1) << 3) | (((nl >> 3) & 1) << 2);
        size_t base = (((size_t)(b * NH + h) * 32 + (n >> 5)) * 2048) + 1024
                    + (size_t)((kp >> 3) * 256 + (kp & 7));
        kv[base + (size_t)(d0 + 0) * 8] = f2bf(v0);
        kv[base + (size_t)(d0 + 1) * 8] = f2bf(v1);
        kv[base + (size_t)(d0 + 2) * 8] = f2bf(v2);
        kv[base + (size_t)(d0 + 3) * 8] = f2bf(v3);
      }
    }
  }
}

// ---------------- Kernel 3: flash attention, strict causal -------------------
// R17 structure extended pair->QUAD per barrier: each iteration stages FOUR
// K/V tiles (16KB, two gl_lds16 calls per thread) double-buffered, and each
// wave runs up to 4 tile-computes between barriers (5 avg barriers/block).
// Longest groups first. Swapped QK^T 32x32x16, log2-domain scores, bare
// v_exp, cvt_pk pack, plane-major LDS layout (conflict-free b128).
__global__ __launch_bounds__(512, 4) void k_attn(
    const unsigned short* __restrict__ qws, const unsigned short* __restrict__ kv,
    float* __restrict__ out) {
  __shared__ __align__(16) unsigned short kvbuf[2][8192];   // quad buffers, 32KB
  int tid = threadIdx.x;
  int wid = tid >> 6, l = tid & 63;
  int col = l & 31, hi = l >> 5;
  int bh = (int)(blockIdx.x & 255);                   // XCD-pinned (256%8==0)
  int g  = 3 - (int)(blockIdx.x >> 8);                // longest groups first
  int qt = g * 8 + wid;                               // this wave's q-tile
  int q0 = qt << 5;
  int niter = g * 2 + 2;                              // quad-iterations

  const unsigned short* Q   = qws + (size_t)bh * S_ * HD;
  const unsigned short* kvb = kv + (size_t)bh * 32 * 2048;
  char* kb0 = (char*)&kvbuf[0][0];                    // buffer byte bases
  int wb = wid * 1024;                                // tid*16 = wid*1024+lane*16

  short8 aq0 = *reinterpret_cast<const short8*>(Q + (q0 + col) * HD + hi * 8);
  short8 aq1 = *reinterpret_cast<const short8*>(Q + (q0 + col) * HD + 16 + hi * 8);

  f32x16 z, O;
  #pragma unroll
  for (int i = 0; i < 16; ++i) { z[i] = 0.f; O[i] = 0.f; }
  float lsA = 0.f, lsB = 0.f;

  gl_lds16(kvb + tid * 8,        kb0 + wb);           // prologue: DMA quad 0
  gl_lds16(kvb + 4096 + tid * 8, kb0 + 8192 + wb);
  __syncthreads();

  #pragma unroll 1
  for (int i = 0; i < niter; ++i) {
    int cur = i & 1;
    bool more = (i + 1 < niter);
    if (more) {                                       // DMA next quad into cur^1
      const unsigned short* src = kvb + (size_t)(i + 1) * 8192 + tid * 8;
      char* dst = kb0 + (cur ^ 1) * 16384 + wb;
      gl_lds16(src,        dst);
      gl_lds16(src + 4096, dst + 8192);
    }

    #pragma unroll
    for (int sub = 0; sub < 4; ++sub) {
      int t = 4 * i + sub;
      if (qt >= t) {                                  // wave-uniform
        const unsigned short* Kb = &kvbuf[cur][sub * 2048];
        short8 bk0 = *reinterpret_cast<const short8*>(Kb + hi * 256 + col * 8);
        short8 bk1 = *reinterpret_cast<const short8*>(Kb + 512 + hi * 256 + col * 8);
        short8 av0 = *reinterpret_cast<const short8*>(Kb + 1024 + hi * 256 + col * 8);
        short8 av1 = *reinterpret_cast<const short8*>(Kb + 1536 + hi * 256 + col * 8);

        f32x16 st = __builtin_amdgcn_mfma_f32_32x32x16_bf16(bk0, aq0, z, 0, 0, 0);
        st = __builtin_amdgcn_mfma_f32_32x32x16_bf16(bk1, aq1, st, 0, 0, 0);

        float p[16];
        if (t == qt) {                                // diagonal: strict mask
          #pragma unroll
          for (int r = 0; r < 16; ++r) {
            int key = (r & 3) + 8 * (r >> 2) + 4 * hi;
            float e = __builtin_amdgcn_exp2f(st[r]);
            p[r] = (key < col) ? e : 0.f;
          }
        } else {
          #pragma unroll
          for (int r = 0; r < 16; ++r) p[r] = __builtin_amdgcn_exp2f(st[r]);
        }

        lsA += ((p[0] + p[1]) + (p[2] + p[3])) + ((p[4] + p[5]) + (p[6] + p[7]));
        lsB += ((p[8] + p[9]) + (p[10] + p[11])) + ((p[12] + p[13]) + (p[14] + p[15]));

        union { unsigned int u[8]; short8 v[2]; } pb;
        #pragma unroll
        for (int jj = 0; jj < 8; ++jj)
          asm("v_cvt_pk_bf16_f32 %0, %1, %2"
              : "=v"(pb.u[jj]) : "v"(p[2 * jj]), "v"(p[2 * jj + 1]));

        O = __builtin_amdgcn_mfma_f32_32x32x16_bf16(av0, pb.v[0], O, 0, 0, 0);
        O = __builtin_amdgcn_mfma_f32_32x32x16_bf16(av1, pb.v[1], O, 0, 0, 0);
      }
    }

    __syncthreads();                                  // drains vmcnt: DMA landed
  }

  float lsum = lsA + lsB;
  float ltot = lsum + __shfl_xor(lsum, 32);
  float linv = (ltot > 0.f) ? 1.f / ltot : 0.f;       // q==0 row -> all zeros
  int b = bh >> 3, h = bh & 7;
  float* ob = out + ((size_t)(b * 256 + h * 32)) * S_ + q0 + col;
  #pragma unroll
  for (int r = 0; r < 16; ++r) {
    int d = (r & 3) + 8 * (r >> 2) + 4 * hi;
    ob[(size_t)d * S_] = O[r] * linv;
  }
}

// ---------------------------------------------------------------------------
extern "C" void kernel_launch(void* const* d_in, const int* in_sizes, int n_in,
                              void* d_out, int out_size, void* d_ws, size_t ws_size,
                              hipStream_t stream) {
  const float* x   = (const float*)d_in[0];
  const float* qw  = (const float*)d_in[1];
  const float* qb  = (const float*)d_in[2];
  const float* kvw = (const float*)d_in[3];
  const float* kvb = (const float*)d_in[4];
  float* out = (float*)d_out;

  char* ws = (char*)d_ws;
  unsigned short* wt   = (unsigned short*)(ws + 0);         //   768*256*2 = 393216
  float*          bias = (float*)(ws + 393216);             //   768*4     = 3072
  unsigned short* xt   = (unsigned short*)(ws + 396288);    //  32*1024*256*2
  unsigned short* qws  = (unsigned short*)(ws + 17173504);  //  32*8*1024*32*2
  unsigned short* kv   = (unsigned short*)(ws + 33950720);  //  256*32*2048*2 = 33554432
                                                            //  ends at 67505152

  k_prep<<<8960, 256, 0, stream>>>(x, xt, qw, qb, kvw, kvb, wt, bias);
  k_proj<<<dim3(48, 32), 256, 0, stream>>>(wt, bias, xt, qws, kv);
  k_attn<<<1024, 512, 0, stream>>>(qws, kv, out);
}

// Round 4
// 70.940 us; speedup vs baseline: 1.3681x; 1.3681x over previous
//
#include <hip/hip_runtime.h>
#include <hip/hip_bf16.h>

typedef __attribute__((ext_vector_type(8))) short short8;
typedef __attribute__((ext_vector_type(4))) float f32x4;
typedef __attribute__((ext_vector_type(16))) float f32x16;

#define B_  32
#define CH  256
#define S_  1024
#define NH  8
#define HD  32

static __device__ __forceinline__ unsigned short f2bf(float f) {
  __hip_bfloat16 h = __float2bfloat16(f);
  return *reinterpret_cast<unsigned short*>(&h);
}

// Async global->LDS DMA, 16B per lane. LDS dest = wave-uniform base + lane*16.
static __device__ __forceinline__ void gl_lds16(const void* g, void* l) {
  __builtin_amdgcn_global_load_lds(
      (const __attribute__((address_space(1))) void*)g,
      (__attribute__((address_space(3))) void*)l, 16, 0, 0);
}

// ---------------- Kernel 1: prep = xpose (blocks 0..8191) + wconv (8192..) ---
// xpose: x (B,C,S) fp32 -> xt (B,S,C) bf16 via 32x32 LDS tile.
// wconv: fold (1/sqrt(32))*log2(e) into Q weights+bias, convert to bf16;
// scores then live in the log2 domain -> softmax exp is a bare v_exp_f32.
__global__ void k_prep(const float* __restrict__ x, unsigned short* __restrict__ xt,
                       const float* __restrict__ qw, const float* __restrict__ qb,
                       const float* __restrict__ kvw, const float* __restrict__ kvb,
                       unsigned short* __restrict__ wt, float* __restrict__ bias) {
  __shared__ float tile[32][33];
  int blk = (int)blockIdx.x;
  int t = threadIdx.x;
  if (blk < 8192) {                                   // ---- xpose ----
    int b = blk >> 8;
    int inner = blk & 255;
    int ct = inner >> 5, st = inner & 31;             // 8 c-tiles x 32 s-tiles
    int c0 = ct * 32, s0 = st * 32;
    int r = t >> 3, q4 = (t & 7) * 4;
    const float4 v = *reinterpret_cast<const float4*>(
        x + ((size_t)(b * CH + c0 + r)) * S_ + s0 + q4);
    tile[r][q4 + 0] = v.x; tile[r][q4 + 1] = v.y;
    tile[r][q4 + 2] = v.z; tile[r][q4 + 3] = v.w;
    __syncthreads();
    ushort4 u;
    u.x = f2bf(tile[q4 + 0][r]); u.y = f2bf(tile[q4 + 1][r]);
    u.z = f2bf(tile[q4 + 2][r]); u.w = f2bf(tile[q4 + 3][r]);
    *reinterpret_cast<ushort4*>(xt + ((size_t)(b * S_ + s0 + r)) * CH + c0 + q4) = u;
  } else {                                            // ---- wconv ----
    int gid = (blk - 8192) * 256 + t;                 // 0..196607
    const float rs = 0.25503531838951954f;            // log2(e)/sqrt(32)
    int o = gid >> 8, c = gid & 255;
    float v = (o < 256) ? qw[o * 256 + c] * rs : kvw[(o - 256) * 256 + c];
    wt[gid] = f2bf(v);
    if (gid < 768) bias[gid] = (gid < 256) ? qb[gid] * rs : kvb[gid - 256];
  }
}

// ---------------- Kernel 2: projection GEMM (768x1024x256 per batch) ---------
// R21: loop reverted to the proven R17 form VERBATIM (2-phase double-buffered
// global_load_lds, [row][kb][8] layout, __syncthreads drain — measured 40.8us,
// the best of R17/R19/R20; load path is at minimum VMEM requests). NEW: the
// K- and V-block epilogues are staged through LDS. Theory: V-blocks' 64
// scalar 2B scatter stores/thread (each wave-instr hitting 16 lines) made
// mt=4,5 blocks run ~3-4x longer than Q/K blocks -> store-bound tail at ~2
// blocks/CU = the observed low-everything profile. Now: write the 128x128
// tile into LDS (reusing the 32KB staging union after the last barrier) in
// the exact kv-target layout, barrier, then copy out as 8 fully-coalesced
// 16B stores/thread (consecutive lanes -> contiguous 256B).
// K and V global layout (PLANE-MAJOR PER-TILE, what k_attn stages):
//   kv[bh][t][0..1023]   : K-tile - plane p (dims 8p..8p+7) x 32 keys x 8
//   kv[bh][t][1024..2047]: V-tile - plane s (sigma-keys 8s..8s+7) x 32 dims x 8
// sigma = swap bits 2<->3 of the local key index (PV B-fragment order).
__global__ __launch_bounds__(256) void k_proj(
    const unsigned short* __restrict__ wt, const float* __restrict__ bias,
    const unsigned short* __restrict__ xt,
    unsigned short* __restrict__ qws, unsigned short* __restrict__ kv) {
  __shared__ __align__(16) union {
    struct { unsigned short As[2][4096]; unsigned short Bs[2][4096]; } g;
    unsigned short vst[16384];                        // epilogue staging, 32KB
  } SH;
  int b = blockIdx.y;
  int mt = blockIdx.x >> 3, nt = blockIdx.x & 7;      // 6 m-tiles x 8 n-tiles
  int tid = threadIdx.x;
  int wid = tid >> 6, l = tid & 63;
  int rb = l >> 4, lr = l & 15;
  int wr = wid >> 1, wc = wid & 1;
  int mb = mt * 128, nb = nt * 128;                   // block tile bases
  int wm = wr * 64, wn = wc * 64;                     // wave offsets in tile
  const unsigned short* xb = xt + (size_t)b * S_ * CH;

  int r0 = tid >> 2, k0 = (tid & 3) * 8;
  int r1 = (tid + 256) >> 2, k1 = ((tid + 256) & 3) * 8;
  const unsigned short* wa0 = wt + (size_t)(mb + r0) * CH + k0;
  const unsigned short* wa1 = wt + (size_t)(mb + r1) * CH + k1;
  const unsigned short* xb0 = xb + (size_t)(nb + r0) * CH + k0;
  const unsigned short* xb1 = xb + (size_t)(nb + r1) * CH + k1;
  char* asb = (char*)&SH.g.As[0][0];
  char* bsb = (char*)&SH.g.Bs[0][0];
  int wb = wid * 1024;                                // tid*16 = wid*1024+lane*16

  f32x4 acc[4][4];
  #pragma unroll
  for (int mf = 0; mf < 4; ++mf)
    #pragma unroll
    for (int nf = 0; nf < 4; ++nf)
      acc[mf][nf] = (f32x4){0.f, 0.f, 0.f, 0.f};

  gl_lds16(wa0, asb + wb);
  gl_lds16(wa1, asb + 4096 + wb);
  gl_lds16(xb0, bsb + wb);
  gl_lds16(xb1, bsb + 4096 + wb);
  __syncthreads();

  #pragma unroll 1
  for (int kk = 0; kk < 8; ++kk) {
    int cur = kk & 1;
    bool more = (kk < 7);
    if (more) {                                       // DMA next step into cur^1
      int ko = (kk + 1) * 32;
      int bo = (cur ^ 1) * 8192 + wb;
      gl_lds16(wa0 + ko, asb + bo);
      gl_lds16(wa1 + ko, asb + 4096 + bo);
      gl_lds16(xb0 + ko, bsb + bo);
      gl_lds16(xb1 + ko, bsb + 4096 + bo);
    }

    short8 a[4], bfr[4];
    #pragma unroll
    for (int mf = 0; mf < 4; ++mf)
      a[mf] = *reinterpret_cast<const short8*>(
          &SH.g.As[cur][(wm + mf * 16 + lr) * 32 + rb * 8]);
    #pragma unroll
    for (int nf = 0; nf < 4; ++nf)
      bfr[nf] = *reinterpret_cast<const short8*>(
          &SH.g.Bs[cur][(wn + nf * 16 + lr) * 32 + rb * 8]);
    #pragma unroll
    for (int mf = 0; mf < 4; ++mf)
      #pragma unroll
      for (int nf = 0; nf < 4; ++nf)
        acc[mf][nf] = __builtin_amdgcn_mfma_f32_16x16x32_bf16(
            a[mf], bfr[nf], acc[mf][nf], 0, 0, 0);

    __syncthreads();                                  // drains vmcnt: DMA landed
  }

  if (mb < 256) {
    // ---- Q blocks (mt 0,1): direct stores, unchanged from R17 ----
    #pragma unroll
    for (int mf = 0; mf < 4; ++mf) {
      int m0 = mb + wm + mf * 16 + rb * 4;
      const float4 bv = *reinterpret_cast<const float4*>(bias + m0);
      #pragma unroll
      for (int nf = 0; nf < 4; ++nf) {
        int n = nb + wn + nf * 16 + lr;
        ushort4 u = {f2bf(acc[mf][nf][0] + bv.x), f2bf(acc[mf][nf][1] + bv.y),
                     f2bf(acc[mf][nf][2] + bv.z), f2bf(acc[mf][nf][3] + bv.w)};
        int h = m0 >> 5, d = m0 & 31;
        *reinterpret_cast<ushort4*>(
            qws + ((size_t)(b * NH + h) * S_ + n) * HD + d) = u;
      }
    }
  } else {
    // ---- K blocks (mt 2,3) / V blocks (mt 4,5): stage tile in LDS in the
    // exact kv-target layout, then coalesced 16B copy-out. Block-uniform
    // branch (mb fixed per block) -> __syncthreads is safe.
    const bool isV = (mb >= 512);
    const int voff = isV ? 1024 : 0;
    unsigned short* vst = SH.vst;
    #pragma unroll
    for (int mf = 0; mf < 4; ++mf) {
      int m0 = mb + wm + mf * 16 + rb * 4;
      const float4 bv = *reinterpret_cast<const float4*>(bias + m0);
      int mml = wm + mf * 16 + rb * 4;                // 0..127 (local row)
      int hl = mml >> 5, d0 = mml & 31;               // local head, dims d0..d0+3
      #pragma unroll
      for (int nf = 0; nf < 4; ++nf) {
        int nlc = wn + nf * 16 + lr;                  // 0..127 (local key)
        int tl = nlc >> 5, nl = nlc & 31;             // local tile, key-in-tile
        float v0 = acc[mf][nf][0] + bv.x;
        float v1 = acc[mf][nf][1] + bv.y;
        float v2 = acc[mf][nf][2] + bv.z;
        float v3 = acc[mf][nf][3] + bv.w;
        int tb = (hl * 4 + tl) * 1024;                // local (head,tile) base
        if (isV) {                                    // sigma: swap bits 2,3
          int kp = (nl & 19) | (((nl >> 2) & 1) << 3) | (((nl >> 3) & 1) << 2);
          int base = tb + (kp >> 3) * 256 + (kp & 7);
          vst[base + (size_t)(d0 + 0) * 8] = f2bf(v0);
          vst[base + (size_t)(d0 + 1) * 8] = f2bf(v1);
          vst[base + (size_t)(d0 + 2) * 8] = f2bf(v2);
          vst[base + (size_t)(d0 + 3) * 8] = f2bf(v3);
        } else {
          ushort4 u = {f2bf(v0), f2bf(v1), f2bf(v2), f2bf(v3)};
          *reinterpret_cast<ushort4*>(
              &vst[tb + (d0 >> 3) * 256 + nl * 8 + (d0 & 7)]) = u;
        }
      }
    }
    __syncthreads();
    // Copy-out: 16 threads per (head,tile) 2KB chunk; lane j covers granules
    // j, j+16, ..., j+112 -> consecutive lanes = contiguous 256B per s.
    int tt = tid >> 4, j = tid & 15;
    int hb = (isV ? (mb - 512) : (mb - 256)) >> 5;
    int h = hb + (tt >> 2);
    size_t gb = ((size_t)(b * NH + h) * 32 + (nt * 4 + (tt & 3))) * 2048 + voff;
    #pragma unroll
    for (int s = 0; s < 8; ++s) {
      int off = (j + s * 16) * 8;                     // shorts, 16B-aligned
      *reinterpret_cast<short8*>(kv + gb + off) =
          *reinterpret_cast<const short8*>(vst + tt * 1024 + off);
    }
  }
}

// ---------------- Kernel 3: flash attention, strict causal -------------------
// R17 structure extended pair->QUAD per barrier: each iteration stages FOUR
// K/V tiles (16KB, two gl_lds16 calls per thread) double-buffered, and each
// wave runs up to 4 tile-computes between barriers (5 avg barriers/block).
// Longest groups first. Swapped QK^T 32x32x16, log2-domain scores, bare
// v_exp, cvt_pk pack, plane-major LDS layout (conflict-free b128).
__global__ __launch_bounds__(512, 4) void k_attn(
    const unsigned short* __restrict__ qws, const unsigned short* __restrict__ kv,
    float* __restrict__ out) {
  __shared__ __align__(16) unsigned short kvbuf[2][8192];   // quad buffers, 32KB
  int tid = threadIdx.x;
  int wid = tid >> 6, l = tid & 63;
  int col = l & 31, hi = l >> 5;
  int bh = (int)(blockIdx.x & 255);                   // XCD-pinned (256%8==0)
  int g  = 3 - (int)(blockIdx.x >> 8);                // longest groups first
  int qt = g * 8 + wid;                               // this wave's q-tile
  int q0 = qt << 5;
  int niter = g * 2 + 2;                              // quad-iterations

  const unsigned short* Q   = qws + (size_t)bh * S_ * HD;
  const unsigned short* kvb = kv + (size_t)bh * 32 * 2048;
  char* kb0 = (char*)&kvbuf[0][0];                    // buffer byte bases
  int wb = wid * 1024;                                // tid*16 = wid*1024+lane*16

  short8 aq0 = *reinterpret_cast<const short8*>(Q + (q0 + col) * HD + hi * 8);
  short8 aq1 = *reinterpret_cast<const short8*>(Q + (q0 + col) * HD + 16 + hi * 8);

  f32x16 z, O;
  #pragma unroll
  for (int i = 0; i < 16; ++i) { z[i] = 0.f; O[i] = 0.f; }
  float lsA = 0.f, lsB = 0.f;

  gl_lds16(kvb + tid * 8,        kb0 + wb);           // prologue: DMA quad 0
  gl_lds16(kvb + 4096 + tid * 8, kb0 + 8192 + wb);
  __syncthreads();

  #pragma unroll 1
  for (int i = 0; i < niter; ++i) {
    int cur = i & 1;
    bool more = (i + 1 < niter);
    if (more) {                                       // DMA next quad into cur^1
      const unsigned short* src = kvb + (size_t)(i + 1) * 8192 + tid * 8;
      char* dst = kb0 + (cur ^ 1) * 16384 + wb;
      gl_lds16(src,        dst);
      gl_lds16(src + 4096, dst + 8192);
    }

    #pragma unroll
    for (int sub = 0; sub < 4; ++sub) {
      int t = 4 * i + sub;
      if (qt >= t) {                                  // wave-uniform
        const unsigned short* Kb = &kvbuf[cur][sub * 2048];
        short8 bk0 = *reinterpret_cast<const short8*>(Kb + hi * 256 + col * 8);
        short8 bk1 = *reinterpret_cast<const short8*>(Kb + 512 + hi * 256 + col * 8);
        short8 av0 = *reinterpret_cast<const short8*>(Kb + 1024 + hi * 256 + col * 8);
        short8 av1 = *reinterpret_cast<const short8*>(Kb + 1536 + hi * 256 + col * 8);

        f32x16 st = __builtin_amdgcn_mfma_f32_32x32x16_bf16(bk0, aq0, z, 0, 0, 0);
        st = __builtin_amdgcn_mfma_f32_32x32x16_bf16(bk1, aq1, st, 0, 0, 0);

        float p[16];
        if (t == qt) {                                // diagonal: strict mask
          #pragma unroll
          for (int r = 0; r < 16; ++r) {
            int key = (r & 3) + 8 * (r >> 2) + 4 * hi;
            float e = __builtin_amdgcn_exp2f(st[r]);
            p[r] = (key < col) ? e : 0.f;
          }
        } else {
          #pragma unroll
          for (int r = 0; r < 16; ++r) p[r] = __builtin_amdgcn_exp2f(st[r]);
        }

        lsA += ((p[0] + p[1]) + (p[2] + p[3])) + ((p[4] + p[5]) + (p[6] + p[7]));
        lsB += ((p[8] + p[9]) + (p[10] + p[11])) + ((p[12] + p[13]) + (p[14] + p[15]));

        union { unsigned int u[8]; short8 v[2]; } pb;
        #pragma unroll
        for (int jj = 0; jj < 8; ++jj)
          asm("v_cvt_pk_bf16_f32 %0, %1, %2"
              : "=v"(pb.u[jj]) : "v"(p[2 * jj]), "v"(p[2 * jj + 1]));

        O = __builtin_amdgcn_mfma_f32_32x32x16_bf16(av0, pb.v[0], O, 0, 0, 0);
        O = __builtin_amdgcn_mfma_f32_32x32x16_bf16(av1, pb.v[1], O, 0, 0, 0);
      }
    }

    __syncthreads();                                  // drains vmcnt: DMA landed
  }

  float lsum = lsA + lsB;
  float ltot = lsum + __shfl_xor(lsum, 32);
  float linv = (ltot > 0.f) ? 1.f / ltot : 0.f;       // q==0 row -> all zeros
  int b = bh >> 3, h = bh & 7;
  float* ob = out + ((size_t)(b * 256 + h * 32)) * S_ + q0 + col;
  #pragma unroll
  for (int r = 0; r < 16; ++r) {
    int d = (r & 3) + 8 * (r >> 2) + 4 * hi;
    ob[(size_t)d * S_] = O[r] * linv;
  }
}

// ---------------------------------------------------------------------------
extern "C" void kernel_launch(void* const* d_in, const int* in_sizes, int n_in,
                              void* d_out, int out_size, void* d_ws, size_t ws_size,
                              hipStream_t stream) {
  const float* x   = (const float*)d_in[0];
  const float* qw  = (const float*)d_in[1];
  const float* qb  = (const float*)d_in[2];
  const float* kvw = (const float*)d_in[3];
  const float* kvb = (const float*)d_in[4];
  float* out = (float*)d_out;

  char* ws = (char*)d_ws;
  unsigned short* wt   = (unsigned short*)(ws + 0);         //   768*256*2 = 393216
  float*          bias = (float*)(ws + 393216);             //   768*4     = 3072
  unsigned short* xt   = (unsigned short*)(ws + 396288);    //  32*1024*256*2
  unsigned short* qws  = (unsigned short*)(ws + 17173504);  //  32*8*1024*32*2
  unsigned short* kv   = (unsigned short*)(ws + 33950720);  //  256*32*2048*2 = 33554432
                                                            //  ends at 67505152

  k_prep<<<8960, 256, 0, stream>>>(x, xt, qw, qb, kvw, kvb, wt, bias);
  k_proj<<<dim3(48, 32), 256, 0, stream>>>(wt, bias, xt, qws, kv);
  k_attn<<<1024, 512, 0, stream>>>(qws, kv, out);
}

// Round 5
// 68.449 us; speedup vs baseline: 1.4179x; 1.0364x over previous
//
#include <hip/hip_runtime.h>
#include <hip/hip_bf16.h>

typedef __attribute__((ext_vector_type(8))) short short8;
typedef __attribute__((ext_vector_type(4))) float f32x4;
typedef __attribute__((ext_vector_type(16))) float f32x16;

#define B_  32
#define CH  256
#define S_  1024
#define NH  8
#define HD  32

static __device__ __forceinline__ unsigned short f2bf(float f) {
  __hip_bfloat16 h = __float2bfloat16(f);
  return *reinterpret_cast<unsigned short*>(&h);
}

// Async global->LDS DMA, 16B per lane. LDS dest = wave-uniform base + lane*16.
static __device__ __forceinline__ void gl_lds16(const void* g, void* l) {
  __builtin_amdgcn_global_load_lds(
      (const __attribute__((address_space(1))) void*)g,
      (__attribute__((address_space(3))) void*)l, 16, 0, 0);
}

// ---------------- Kernel 1: prep = xpose (blocks 0..8191) + wconv (8192..) ---
// xpose: x (B,C,S) fp32 -> xt (B,S,C) bf16 via 32x32 LDS tile.
// wconv: fold (1/sqrt(32))*log2(e) into Q weights+bias, convert to bf16;
// scores then live in the log2 domain -> softmax exp is a bare v_exp_f32.
__global__ void k_prep(const float* __restrict__ x, unsigned short* __restrict__ xt,
                       const float* __restrict__ qw, const float* __restrict__ qb,
                       const float* __restrict__ kvw, const float* __restrict__ kvb,
                       unsigned short* __restrict__ wt, float* __restrict__ bias) {
  __shared__ float tile[32][33];
  int blk = (int)blockIdx.x;
  int t = threadIdx.x;
  if (blk < 8192) {                                   // ---- xpose ----
    int b = blk >> 8;
    int inner = blk & 255;
    int ct = inner >> 5, st = inner & 31;             // 8 c-tiles x 32 s-tiles
    int c0 = ct * 32, s0 = st * 32;
    int r = t >> 3, q4 = (t & 7) * 4;
    const float4 v = *reinterpret_cast<const float4*>(
        x + ((size_t)(b * CH + c0 + r)) * S_ + s0 + q4);
    tile[r][q4 + 0] = v.x; tile[r][q4 + 1] = v.y;
    tile[r][q4 + 2] = v.z; tile[r][q4 + 3] = v.w;
    __syncthreads();
    ushort4 u;
    u.x = f2bf(tile[q4 + 0][r]); u.y = f2bf(tile[q4 + 1][r]);
    u.z = f2bf(tile[q4 + 2][r]); u.w = f2bf(tile[q4 + 3][r]);
    *reinterpret_cast<ushort4*>(xt + ((size_t)(b * S_ + s0 + r)) * CH + c0 + q4) = u;
  } else {                                            // ---- wconv ----
    int gid = (blk - 8192) * 256 + t;                 // 0..196607
    const float rs = 0.25503531838951954f;            // log2(e)/sqrt(32)
    int o = gid >> 8, c = gid & 255;
    float v = (o < 256) ? qw[o * 256 + c] * rs : kvw[(o - 256) * 256 + c];
    wt[gid] = f2bf(v);
    if (gid < 768) bias[gid] = (gid < 256) ? qb[gid] * rs : kvb[gid - 256];
  }
}

// ---------------- Kernel 2: projection GEMM (768x1024x256 per batch) ---------
// R22: R21's proven schedule (2-phase double-buffered global_load_lds,
// [row][32] LDS layout, __syncthreads drain, LDS-staged coalesced K/V
// epilogue) but with 512-THREAD / 8-WAVE BLOCKS (wave tile 64x32, acc[4][2]).
// Theory: at 256 threads only ~2 blocks/CU (8 waves) were resident and all
// blocks sat in lockstep at the per-step vmcnt drain -> CU idle every step.
// Same tile, same DMA bytes, but 2-4 blocks/CU x 8 waves = 20-32 waves/CU:
// other blocks' waves cover each drain. VGPR drops (acc 32 vs 64).
// Per step: ONE A-call + ONE B-call per thread (512 x 16B = 8KB each).
// K and V global layout (PLANE-MAJOR PER-TILE, what k_attn stages):
//   kv[bh][t][0..1023]   : K-tile - plane p (dims 8p..8p+7) x 32 keys x 8
//   kv[bh][t][1024..2047]: V-tile - plane s (sigma-keys 8s..8s+7) x 32 dims x 8
// sigma = swap bits 2<->3 of the local key index (PV B-fragment order).
__global__ __launch_bounds__(512) void k_proj(
    const unsigned short* __restrict__ wt, const float* __restrict__ bias,
    const unsigned short* __restrict__ xt,
    unsigned short* __restrict__ qws, unsigned short* __restrict__ kv) {
  __shared__ __align__(16) union {
    struct { unsigned short As[2][4096]; unsigned short Bs[2][4096]; } g;
    unsigned short vst[16384];                        // epilogue staging, 32KB
  } SH;
  int b = blockIdx.y;
  int mt = blockIdx.x >> 3, nt = blockIdx.x & 7;      // 6 m-tiles x 8 n-tiles
  int tid = threadIdx.x;
  int wid = tid >> 6, l = tid & 63;
  int rb = l >> 4, lr = l & 15;
  int wr = wid >> 2, wc = wid & 3;                    // 2 x 4 wave grid
  int mb = mt * 128, nb = nt * 128;                   // block tile bases
  int wm = wr * 64, wn = wc * 32;                     // wave offsets in tile
  const unsigned short* xb = xt + (size_t)b * S_ * CH;

  int r0 = tid >> 2, k0 = (tid & 3) * 8;              // 128 rows x 4 k-chunks
  const unsigned short* wa0 = wt + (size_t)(mb + r0) * CH + k0;
  const unsigned short* xb0 = xb + (size_t)(nb + r0) * CH + k0;
  char* asb = (char*)&SH.g.As[0][0];
  char* bsb = (char*)&SH.g.Bs[0][0];
  int wb = wid * 1024;                                // tid*16 = wid*1024+lane*16

  f32x4 acc[4][2];
  #pragma unroll
  for (int mf = 0; mf < 4; ++mf)
    #pragma unroll
    for (int nf = 0; nf < 2; ++nf)
      acc[mf][nf] = (f32x4){0.f, 0.f, 0.f, 0.f};

  gl_lds16(wa0, asb + wb);
  gl_lds16(xb0, bsb + wb);
  __syncthreads();

  #pragma unroll 1
  for (int kk = 0; kk < 8; ++kk) {
    int cur = kk & 1;
    bool more = (kk < 7);
    if (more) {                                       // DMA next step into cur^1
      int ko = (kk + 1) * 32;
      int bo = (cur ^ 1) * 8192 + wb;
      gl_lds16(wa0 + ko, asb + bo);
      gl_lds16(xb0 + ko, bsb + bo);
    }

    short8 a[4], bfr[2];
    #pragma unroll
    for (int mf = 0; mf < 4; ++mf)
      a[mf] = *reinterpret_cast<const short8*>(
          &SH.g.As[cur][(wm + mf * 16 + lr) * 32 + rb * 8]);
    #pragma unroll
    for (int nf = 0; nf < 2; ++nf)
      bfr[nf] = *reinterpret_cast<const short8*>(
          &SH.g.Bs[cur][(wn + nf * 16 + lr) * 32 + rb * 8]);
    #pragma unroll
    for (int mf = 0; mf < 4; ++mf)
      #pragma unroll
      for (int nf = 0; nf < 2; ++nf)
        acc[mf][nf] = __builtin_amdgcn_mfma_f32_16x16x32_bf16(
            a[mf], bfr[nf], acc[mf][nf], 0, 0, 0);

    __syncthreads();                                  // drains vmcnt: DMA landed
  }

  if (mb < 256) {
    // ---- Q blocks (mt 0,1): direct stores ----
    #pragma unroll
    for (int mf = 0; mf < 4; ++mf) {
      int m0 = mb + wm + mf * 16 + rb * 4;
      const float4 bv = *reinterpret_cast<const float4*>(bias + m0);
      #pragma unroll
      for (int nf = 0; nf < 2; ++nf) {
        int n = nb + wn + nf * 16 + lr;
        ushort4 u = {f2bf(acc[mf][nf][0] + bv.x), f2bf(acc[mf][nf][1] + bv.y),
                     f2bf(acc[mf][nf][2] + bv.z), f2bf(acc[mf][nf][3] + bv.w)};
        int h = m0 >> 5, d = m0 & 31;
        *reinterpret_cast<ushort4*>(
            qws + ((size_t)(b * NH + h) * S_ + n) * HD + d) = u;
      }
    }
  } else {
    // ---- K blocks (mt 2,3) / V blocks (mt 4,5): stage tile in LDS in the
    // exact kv-target layout, then coalesced 16B copy-out. Block-uniform
    // branch (mb fixed per block) -> __syncthreads is safe.
    const bool isV = (mb >= 512);
    const int voff = isV ? 1024 : 0;
    unsigned short* vst = SH.vst;
    #pragma unroll
    for (int mf = 0; mf < 4; ++mf) {
      int m0 = mb + wm + mf * 16 + rb * 4;
      const float4 bv = *reinterpret_cast<const float4*>(bias + m0);
      int mml = wm + mf * 16 + rb * 4;                // 0..127 (local row)
      int hl = mml >> 5, d0 = mml & 31;               // local head, dims d0..d0+3
      #pragma unroll
      for (int nf = 0; nf < 2; ++nf) {
        int nlc = wn + nf * 16 + lr;                  // 0..127 (local key)
        int tl = nlc >> 5, nl = nlc & 31;             // local tile, key-in-tile
        float v0 = acc[mf][nf][0] + bv.x;
        float v1 = acc[mf][nf][1] + bv.y;
        float v2 = acc[mf][nf][2] + bv.z;
        float v3 = acc[mf][nf][3] + bv.w;
        int tb = (hl * 4 + tl) * 1024;                // local (head,tile) base
        if (isV) {                                    // sigma: swap bits 2,3
          int kp = (nl & 19) | (((nl >> 2) & 1) << 3) | (((nl >> 3) & 1) << 2);
          int base = tb + (kp >> 3) * 256 + (kp & 7);
          vst[base + (size_t)(d0 + 0) * 8] = f2bf(v0);
          vst[base + (size_t)(d0 + 1) * 8] = f2bf(v1);
          vst[base + (size_t)(d0 + 2) * 8] = f2bf(v2);
          vst[base + (size_t)(d0 + 3) * 8] = f2bf(v3);
        } else {
          ushort4 u = {f2bf(v0), f2bf(v1), f2bf(v2), f2bf(v3)};
          *reinterpret_cast<ushort4*>(
              &vst[tb + (d0 >> 3) * 256 + nl * 8 + (d0 & 7)]) = u;
        }
      }
    }
    __syncthreads();
    // Copy-out: 32 threads per (head,tile) 2KB chunk; lane j covers granules
    // j, j+32, j+64, j+96 -> consecutive lanes = contiguous 512B per s.
    int tt = tid >> 5, j = tid & 31;
    int hb = (isV ? (mb - 512) : (mb - 256)) >> 5;
    int h = hb + (tt >> 2);
    size_t gb = ((size_t)(b * NH + h) * 32 + (nt * 4 + (tt & 3))) * 2048 + voff;
    #pragma unroll
    for (int s = 0; s < 4; ++s) {
      int off = (j + s * 32) * 8;                     // shorts, 16B-aligned
      *reinterpret_cast<short8*>(kv + gb + off) =
          *reinterpret_cast<const short8*>(vst + tt * 1024 + off);
    }
  }
}

// ---------------- Kernel 3: flash attention, strict causal -------------------
// R17 structure extended pair->QUAD per barrier: each iteration stages FOUR
// K/V tiles (16KB, two gl_lds16 calls per thread) double-buffered, and each
// wave runs up to 4 tile-computes between barriers (5 avg barriers/block).
// Longest groups first. Swapped QK^T 32x32x16, log2-domain scores, bare
// v_exp, cvt_pk pack, plane-major LDS layout (conflict-free b128).
__global__ __launch_bounds__(512, 4) void k_attn(
    const unsigned short* __restrict__ qws, const unsigned short* __restrict__ kv,
    float* __restrict__ out) {
  __shared__ __align__(16) unsigned short kvbuf[2][8192];   // quad buffers, 32KB
  int tid = threadIdx.x;
  int wid = tid >> 6, l = tid & 63;
  int col = l & 31, hi = l >> 5;
  int bh = (int)(blockIdx.x & 255);                   // XCD-pinned (256%8==0)
  int g  = 3 - (int)(blockIdx.x >> 8);                // longest groups first
  int qt = g * 8 + wid;                               // this wave's q-tile
  int q0 = qt << 5;
  int niter = g * 2 + 2;                              // quad-iterations

  const unsigned short* Q   = qws + (size_t)bh * S_ * HD;
  const unsigned short* kvb = kv + (size_t)bh * 32 * 2048;
  char* kb0 = (char*)&kvbuf[0][0];                    // buffer byte bases
  int wb = wid * 1024;                                // tid*16 = wid*1024+lane*16

  short8 aq0 = *reinterpret_cast<const short8*>(Q + (q0 + col) * HD + hi * 8);
  short8 aq1 = *reinterpret_cast<const short8*>(Q + (q0 + col) * HD + 16 + hi * 8);

  f32x16 z, O;
  #pragma unroll
  for (int i = 0; i < 16; ++i) { z[i] = 0.f; O[i] = 0.f; }
  float lsA = 0.f, lsB = 0.f;

  gl_lds16(kvb + tid * 8,        kb0 + wb);           // prologue: DMA quad 0
  gl_lds16(kvb + 4096 + tid * 8, kb0 + 8192 + wb);
  __syncthreads();

  #pragma unroll 1
  for (int i = 0; i < niter; ++i) {
    int cur = i & 1;
    bool more = (i + 1 < niter);
    if (more) {                                       // DMA next quad into cur^1
      const unsigned short* src = kvb + (size_t)(i + 1) * 8192 + tid * 8;
      char* dst = kb0 + (cur ^ 1) * 16384 + wb;
      gl_lds16(src,        dst);
      gl_lds16(src + 4096, dst + 8192);
    }

    #pragma unroll
    for (int sub = 0; sub < 4; ++sub) {
      int t = 4 * i + sub;
      if (qt >= t) {                                  // wave-uniform
        const unsigned short* Kb = &kvbuf[cur][sub * 2048];
        short8 bk0 = *reinterpret_cast<const short8*>(Kb + hi * 256 + col * 8);
        short8 bk1 = *reinterpret_cast<const short8*>(Kb + 512 + hi * 256 + col * 8);
        short8 av0 = *reinterpret_cast<const short8*>(Kb + 1024 + hi * 256 + col * 8);
        short8 av1 = *reinterpret_cast<const short8*>(Kb + 1536 + hi * 256 + col * 8);

        f32x16 st = __builtin_amdgcn_mfma_f32_32x32x16_bf16(bk0, aq0, z, 0, 0, 0);
        st = __builtin_amdgcn_mfma_f32_32x32x16_bf16(bk1, aq1, st, 0, 0, 0);

        float p[16];
        if (t == qt) {                                // diagonal: strict mask
          #pragma unroll
          for (int r = 0; r < 16; ++r) {
            int key = (r & 3) + 8 * (r >> 2) + 4 * hi;
            float e = __builtin_amdgcn_exp2f(st[r]);
            p[r] = (key < col) ? e : 0.f;
          }
        } else {
          #pragma unroll
          for (int r = 0; r < 16; ++r) p[r] = __builtin_amdgcn_exp2f(st[r]);
        }

        lsA += ((p[0] + p[1]) + (p[2] + p[3])) + ((p[4] + p[5]) + (p[6] + p[7]));
        lsB += ((p[8] + p[9]) + (p[10] + p[11])) + ((p[12] + p[13]) + (p[14] + p[15]));

        union { unsigned int u[8]; short8 v[2]; } pb;
        #pragma unroll
        for (int jj = 0; jj < 8; ++jj)
          asm("v_cvt_pk_bf16_f32 %0, %1, %2"
              : "=v"(pb.u[jj]) : "v"(p[2 * jj]), "v"(p[2 * jj + 1]));

        O = __builtin_amdgcn_mfma_f32_32x32x16_bf16(av0, pb.v[0], O, 0, 0, 0);
        O = __builtin_amdgcn_mfma_f32_32x32x16_bf16(av1, pb.v[1], O, 0, 0, 0);
      }
    }

    __syncthreads();                                  // drains vmcnt: DMA landed
  }

  float lsum = lsA + lsB;
  float ltot = lsum + __shfl_xor(lsum, 32);
  float linv = (ltot > 0.f) ? 1.f / ltot : 0.f;       // q==0 row -> all zeros
  int b = bh >> 3, h = bh & 7;
  float* ob = out + ((size_t)(b * 256 + h * 32)) * S_ + q0 + col;
  #pragma unroll
  for (int r = 0; r < 16; ++r) {
    int d = (r & 3) + 8 * (r >> 2) + 4 * hi;
    ob[(size_t)d * S_] = O[r] * linv;
  }
}

// ---------------------------------------------------------------------------
extern "C" void kernel_launch(void* const* d_in, const int* in_sizes, int n_in,
                              void* d_out, int out_size, void* d_ws, size_t ws_size,
                              hipStream_t stream) {
  const float* x   = (const float*)d_in[0];
  const float* qw  = (const float*)d_in[1];
  const float* qb  = (const float*)d_in[2];
  const float* kvw = (const float*)d_in[3];
  const float* kvb = (const float*)d_in[4];
  float* out = (float*)d_out;

  char* ws = (char*)d_ws;
  unsigned short* wt   = (unsigned short*)(ws + 0);         //   768*256*2 = 393216
  float*          bias = (float*)(ws + 393216);             //   768*4     = 3072
  unsigned short* xt   = (unsigned short*)(ws + 396288);    //  32*1024*256*2
  unsigned short* qws  = (unsigned short*)(ws + 17173504);  //  32*8*1024*32*2
  unsigned short* kv   = (unsigned short*)(ws + 33950720);  //  256*32*2048*2 = 33554432
                                                            //  ends at 67505152

  k_prep<<<8960, 256, 0, stream>>>(x, xt, qw, qb, kvw, kvb, wt, bias);
  k_proj<<<dim3(48, 32), 512, 0, stream>>>(wt, bias, xt, qws, kv);
  k_attn<<<1024, 512, 0, stream>>>(qws, kv, out);
}

// Round 8
// 67.665 us; speedup vs baseline: 1.4343x; 1.0116x over previous
//
#include <hip/hip_runtime.h>
#include <hip/hip_bf16.h>

typedef __attribute__((ext_vector_type(8))) short short8;
typedef __attribute__((ext_vector_type(4))) float f32x4;
typedef __attribute__((ext_vector_type(16))) float f32x16;

#define B_  32
#define CH  256
#define S_  1024
#define NH  8
#define HD  32

static __device__ __forceinline__ unsigned short f2bf(float f) {
  __hip_bfloat16 h = __float2bfloat16(f);
  return *reinterpret_cast<unsigned short*>(&h);
}

// Async global->LDS DMA, 16B per lane. LDS dest = wave-uniform base + lane*16.
static __device__ __forceinline__ void gl_lds16(const void* g, void* l) {
  __builtin_amdgcn_global_load_lds(
      (const __attribute__((address_space(1))) void*)g,
      (__attribute__((address_space(3))) void*)l, 16, 0, 0);
}

// ---------------- Kernel 1: prep = xpose (blocks 0..8191) + wconv (8192..) ---
// xpose: x (B,C,S) fp32 -> xt (B,S,C) bf16 via 32x32 LDS tile.
// wconv: fold (1/sqrt(32))*log2(e) into Q weights+bias, convert to bf16;
// scores then live in the log2 domain -> softmax exp is a bare v_exp_f32.
__global__ void k_prep(const float* __restrict__ x, unsigned short* __restrict__ xt,
                       const float* __restrict__ qw, const float* __restrict__ qb,
                       const float* __restrict__ kvw, const float* __restrict__ kvb,
                       unsigned short* __restrict__ wt, float* __restrict__ bias) {
  __shared__ float tile[32][33];
  int blk = (int)blockIdx.x;
  int t = threadIdx.x;
  if (blk < 8192) {                                   // ---- xpose ----
    int b = blk >> 8;
    int inner = blk & 255;
    int ct = inner >> 5, st = inner & 31;             // 8 c-tiles x 32 s-tiles
    int c0 = ct * 32, s0 = st * 32;
    int r = t >> 3, q4 = (t & 7) * 4;
    const float4 v = *reinterpret_cast<const float4*>(
        x + ((size_t)(b * CH + c0 + r)) * S_ + s0 + q4);
    tile[r][q4 + 0] = v.x; tile[r][q4 + 1] = v.y;
    tile[r][q4 + 2] = v.z; tile[r][q4 + 3] = v.w;
    __syncthreads();
    ushort4 u;
    u.x = f2bf(tile[q4 + 0][r]); u.y = f2bf(tile[q4 + 1][r]);
    u.z = f2bf(tile[q4 + 2][r]); u.w = f2bf(tile[q4 + 3][r]);
    *reinterpret_cast<ushort4*>(xt + ((size_t)(b * S_ + s0 + r)) * CH + c0 + q4) = u;
  } else {                                            // ---- wconv ----
    int gid = (blk - 8192) * 256 + t;                 // 0..196607
    const float rs = 0.25503531838951954f;            // log2(e)/sqrt(32)
    int o = gid >> 8, c = gid & 255;
    float v = (o < 256) ? qw[o * 256 + c] * rs : kvw[(o - 256) * 256 + c];
    wt[gid] = f2bf(v);
    if (gid < 768) bias[gid] = (gid < 256) ? qb[gid] * rs : kvb[gid - 256];
  }
}

// ---------------- Kernel 2: projection GEMM (768x1024x256 per batch) ---------
// R25 = R24 + the ONE missing instruction: explicit `s_waitcnt lgkmcnt(0)` +
// sched_barrier(0) between the ds_read cluster and the MFMA cluster (rule #18).
// Root cause of R23/R24's race: MFMAs are register-only, so hipcc sinks the
// MFMA cluster AND its implicit lgkmcnt waits past the barrier; a wave can
// cross barrier k with step-(k-1) ds_reads still outstanding in the LDS
// queue, and another wave's post-barrier prefetch DMA overwrites that buffer
// before the straggler's read executes (intermittent small absmax). The
// explicit LGKM0 pins read-completion BEFORE the wave can reach the next
// barrier -> WAR ledger is closed independent of MFMA placement (this is the
// m201 template's discipline).
// Ledger (2 DMA instrs per step, A+B):
//   prologue: issue step0->b0, step1->b1            (4 outstanding)
//   step k:   VMW(2)   [own step-k DMAs landed; k+1's in flight]
//             s_barrier+sched_barrier(0)  [all waves: step-k DMAs landed,
//                                          step-(k-1) reads complete]
//             issue step k+2 -> buf (k+2)%3          [WAR-safe]
//             ds_read buf k%3; LGKM0                 [reads in regs]
//             MFMAs (free to sink; operands in regs)
// K and V global layout (PLANE-MAJOR PER-TILE, what k_attn stages):
//   kv[bh][t][0..1023]   : K-tile - plane p (dims 8p..8p+7) x 32 keys x 8
//   kv[bh][t][1024..2047]: V-tile - plane s (sigma-keys 8s..8s+7) x 32 dims x 8
// sigma = swap bits 2<->3 of the local key index (PV B-fragment order).

#define VMW(n) asm volatile("s_waitcnt vmcnt(" #n ")" ::: "memory")
#define SBAR() do { __builtin_amdgcn_s_barrier(); \
                    __builtin_amdgcn_sched_barrier(0); } while (0)
#define LGKM0() do { asm volatile("s_waitcnt lgkmcnt(0)" ::: "memory"); \
                     __builtin_amdgcn_sched_barrier(0); } while (0)

#define PROJ_ISSUE(step, buf) do {                                  \
    gl_lds16(wa0 + (step) * 32, asb + (buf) * 8192 + wb);           \
    gl_lds16(xb0 + (step) * 32, bsb + (buf) * 8192 + wb);           \
  } while (0)

#define PROJ_COMPUTE(buf) do {                                      \
    short8 a[4], bfr[2];                                            \
    _Pragma("unroll")                                               \
    for (int mf = 0; mf < 4; ++mf)                                  \
      a[mf] = *reinterpret_cast<const short8*>(                     \
          &SH.g.As[buf][(wm + mf * 16 + lr) * 32 + rb * 8]);        \
    _Pragma("unroll")                                               \
    for (int nf = 0; nf < 2; ++nf)                                  \
      bfr[nf] = *reinterpret_cast<const short8*>(                   \
          &SH.g.Bs[buf][(wn + nf * 16 + lr) * 32 + rb * 8]);        \
    LGKM0();                                                        \
    _Pragma("unroll")                                               \
    for (int mf = 0; mf < 4; ++mf)                                  \
      _Pragma("unroll")                                             \
      for (int nf = 0; nf < 2; ++nf)                                \
        acc[mf][nf] = __builtin_amdgcn_mfma_f32_16x16x32_bf16(      \
            a[mf], bfr[nf], acc[mf][nf], 0, 0, 0);                  \
  } while (0)

__global__ __launch_bounds__(512) void k_proj(
    const unsigned short* __restrict__ wt, const float* __restrict__ bias,
    const unsigned short* __restrict__ xt,
    unsigned short* __restrict__ qws, unsigned short* __restrict__ kv) {
  __shared__ __align__(16) union {
    struct { unsigned short As[3][4096]; unsigned short Bs[3][4096]; } g;
    unsigned short vst[16384];                        // epilogue staging, 32KB
  } SH;                                               // union = 48KB
  int b = blockIdx.y;
  int mt = blockIdx.x >> 3, nt = blockIdx.x & 7;      // 6 m-tiles x 8 n-tiles
  int tid = threadIdx.x;
  int wid = tid >> 6, l = tid & 63;
  int rb = l >> 4, lr = l & 15;
  int wr = wid >> 2, wc = wid & 3;                    // 2 x 4 wave grid
  int mb = mt * 128, nb = nt * 128;                   // block tile bases
  int wm = wr * 64, wn = wc * 32;                     // wave offsets in tile
  const unsigned short* xb = xt + (size_t)b * S_ * CH;

  int r0 = tid >> 2, k0 = (tid & 3) * 8;              // 128 rows x 4 k-chunks
  const unsigned short* wa0 = wt + (size_t)(mb + r0) * CH + k0;
  const unsigned short* xb0 = xb + (size_t)(nb + r0) * CH + k0;
  char* asb = (char*)&SH.g.As[0][0];
  char* bsb = (char*)&SH.g.Bs[0][0];
  int wb = wid * 1024;                                // tid*16 = wid*1024+lane*16

  f32x4 acc[4][2];
  #pragma unroll
  for (int mf = 0; mf < 4; ++mf)
    #pragma unroll
    for (int nf = 0; nf < 2; ++nf)
      acc[mf][nf] = (f32x4){0.f, 0.f, 0.f, 0.f};

  PROJ_ISSUE(0, 0); PROJ_ISSUE(1, 1);                 // prologue: 4 DMAs

  VMW(2); SBAR(); PROJ_ISSUE(2, 2); PROJ_COMPUTE(0);  // step 0
  VMW(2); SBAR(); PROJ_ISSUE(3, 0); PROJ_COMPUTE(1);  // step 1
  VMW(2); SBAR(); PROJ_ISSUE(4, 1); PROJ_COMPUTE(2);  // step 2
  VMW(2); SBAR(); PROJ_ISSUE(5, 2); PROJ_COMPUTE(0);  // step 3
  VMW(2); SBAR(); PROJ_ISSUE(6, 0); PROJ_COMPUTE(1);  // step 4
  VMW(2); SBAR(); PROJ_ISSUE(7, 1); PROJ_COMPUTE(2);  // step 5
  VMW(2); SBAR();                   PROJ_COMPUTE(0);  // step 6
  VMW(0); SBAR();                   PROJ_COMPUTE(1);  // step 7

  if (mb < 256) {
    // ---- Q blocks (mt 0,1): direct stores ----
    #pragma unroll
    for (int mf = 0; mf < 4; ++mf) {
      int m0 = mb + wm + mf * 16 + rb * 4;
      const float4 bv = *reinterpret_cast<const float4*>(bias + m0);
      #pragma unroll
      for (int nf = 0; nf < 2; ++nf) {
        int n = nb + wn + nf * 16 + lr;
        ushort4 u = {f2bf(acc[mf][nf][0] + bv.x), f2bf(acc[mf][nf][1] + bv.y),
                     f2bf(acc[mf][nf][2] + bv.z), f2bf(acc[mf][nf][3] + bv.w)};
        int h = m0 >> 5, d = m0 & 31;
        *reinterpret_cast<ushort4*>(
            qws + ((size_t)(b * NH + h) * S_ + n) * HD + d) = u;
      }
    }
  } else {
    // ---- K blocks (mt 2,3) / V blocks (mt 4,5): stage tile in LDS in the
    // exact kv-target layout, then coalesced 16B copy-out. Block-uniform
    // branch (mb fixed per block) -> __syncthreads is safe.
    __syncthreads();   // all waves' step-6/7 LDS reads done before vst overwrite
    const bool isV = (mb >= 512);
    const int voff = isV ? 1024 : 0;
    unsigned short* vst = SH.vst;
    #pragma unroll
    for (int mf = 0; mf < 4; ++mf) {
      int m0 = mb + wm + mf * 16 + rb * 4;
      const float4 bv = *reinterpret_cast<const float4*>(bias + m0);
      int mml = wm + mf * 16 + rb * 4;                // 0..127 (local row)
      int hl = mml >> 5, d0 = mml & 31;               // local head, dims d0..d0+3
      #pragma unroll
      for (int nf = 0; nf < 2; ++nf) {
        int nlc = wn + nf * 16 + lr;                  // 0..127 (local key)
        int tl = nlc >> 5, nl = nlc & 31;             // local tile, key-in-tile
        float v0 = acc[mf][nf][0] + bv.x;
        float v1 = acc[mf][nf][1] + bv.y;
        float v2 = acc[mf][nf][2] + bv.z;
        float v3 = acc[mf][nf][3] + bv.w;
        int tb = (hl * 4 + tl) * 1024;                // local (head,tile) base
        if (isV) {                                    // sigma: swap bits 2,3
          int kp = (nl & 19) | (((nl >> 2) & 1) << 3) | (((nl >> 3) & 1) << 2);
          int base = tb + (kp >> 3) * 256 + (kp & 7);
          vst[base + (size_t)(d0 + 0) * 8] = f2bf(v0);
          vst[base + (size_t)(d0 + 1) * 8] = f2bf(v1);
          vst[base + (size_t)(d0 + 2) * 8] = f2bf(v2);
          vst[base + (size_t)(d0 + 3) * 8] = f2bf(v3);
        } else {
          ushort4 u = {f2bf(v0), f2bf(v1), f2bf(v2), f2bf(v3)};
          *reinterpret_cast<ushort4*>(
              &vst[tb + (d0 >> 3) * 256 + nl * 8 + (d0 & 7)]) = u;
        }
      }
    }
    __syncthreads();
    // Copy-out: 32 threads per (head,tile) 2KB chunk; lane j covers granules
    // j, j+32, j+64, j+96 -> consecutive lanes = contiguous 512B per s.
    int tt = tid >> 5, j = tid & 31;
    int hb = (isV ? (mb - 512) : (mb - 256)) >> 5;
    int h = hb + (tt >> 2);
    size_t gb = ((size_t)(b * NH + h) * 32 + (nt * 4 + (tt & 3))) * 2048 + voff;
    #pragma unroll
    for (int s = 0; s < 4; ++s) {
      int off = (j + s * 32) * 8;                     // shorts, 16B-aligned
      *reinterpret_cast<short8*>(kv + gb + off) =
          *reinterpret_cast<const short8*>(vst + tt * 1024 + off);
    }
  }
}

// ---------------- Kernel 3: flash attention, strict causal -------------------
// R17 structure extended pair->QUAD per barrier: each iteration stages FOUR
// K/V tiles (16KB, two gl_lds16 calls per thread) double-buffered, and each
// wave runs up to 4 tile-computes between barriers (5 avg barriers/block).
// Longest groups first. Swapped QK^T 32x32x16, log2-domain scores, bare
// v_exp, cvt_pk pack, plane-major LDS layout (conflict-free b128).
__global__ __launch_bounds__(512, 4) void k_attn(
    const unsigned short* __restrict__ qws, const unsigned short* __restrict__ kv,
    float* __restrict__ out) {
  __shared__ __align__(16) unsigned short kvbuf[2][8192];   // quad buffers, 32KB
  int tid = threadIdx.x;
  int wid = tid >> 6, l = tid & 63;
  int col = l & 31, hi = l >> 5;
  int bh = (int)(blockIdx.x & 255);                   // XCD-pinned (256%8==0)
  int g  = 3 - (int)(blockIdx.x >> 8);                // longest groups first
  int qt = g * 8 + wid;                               // this wave's q-tile
  int q0 = qt << 5;
  int niter = g * 2 + 2;                              // quad-iterations

  const unsigned short* Q   = qws + (size_t)bh * S_ * HD;
  const unsigned short* kvb = kv + (size_t)bh * 32 * 2048;
  char* kb0 = (char*)&kvbuf[0][0];                    // buffer byte bases
  int wb = wid * 1024;                                // tid*16 = wid*1024+lane*16

  short8 aq0 = *reinterpret_cast<const short8*>(Q + (q0 + col) * HD + hi * 8);
  short8 aq1 = *reinterpret_cast<const short8*>(Q + (q0 + col) * HD + 16 + hi * 8);

  f32x16 z, O;
  #pragma unroll
  for (int i = 0; i < 16; ++i) { z[i] = 0.f; O[i] = 0.f; }
  float lsA = 0.f, lsB = 0.f;

  gl_lds16(kvb + tid * 8,        kb0 + wb);           // prologue: DMA quad 0
  gl_lds16(kvb + 4096 + tid * 8, kb0 + 8192 + wb);
  __syncthreads();

  #pragma unroll 1
  for (int i = 0; i < niter; ++i) {
    int cur = i & 1;
    bool more = (i + 1 < niter);
    if (more) {                                       // DMA next quad into cur^1
      const unsigned short* src = kvb + (size_t)(i + 1) * 8192 + tid * 8;
      char* dst = kb0 + (cur ^ 1) * 16384 + wb;
      gl_lds16(src,        dst);
      gl_lds16(src + 4096, dst + 8192);
    }

    #pragma unroll
    for (int sub = 0; sub < 4; ++sub) {
      int t = 4 * i + sub;
      if (qt >= t) {                                  // wave-uniform
        const unsigned short* Kb = &kvbuf[cur][sub * 2048];
        short8 bk0 = *reinterpret_cast<const short8*>(Kb + hi * 256 + col * 8);
        short8 bk1 = *reinterpret_cast<const short8*>(Kb + 512 + hi * 256 + col * 8);
        short8 av0 = *reinterpret_cast<const short8*>(Kb + 1024 + hi * 256 + col * 8);
        short8 av1 = *reinterpret_cast<const short8*>(Kb + 1536 + hi * 256 + col * 8);

        f32x16 st = __builtin_amdgcn_mfma_f32_32x32x16_bf16(bk0, aq0, z, 0, 0, 0);
        st = __builtin_amdgcn_mfma_f32_32x32x16_bf16(bk1, aq1, st, 0, 0, 0);

        float p[16];
        if (t == qt) {                                // diagonal: strict mask
          #pragma unroll
          for (int r = 0; r < 16; ++r) {
            int key = (r & 3) + 8 * (r >> 2) + 4 * hi;
            float e = __builtin_amdgcn_exp2f(st[r]);
            p[r] = (key < col) ? e : 0.f;
          }
        } else {
          #pragma unroll
          for (int r = 0; r < 16; ++r) p[r] = __builtin_amdgcn_exp2f(st[r]);
        }

        lsA += ((p[0] + p[1]) + (p[2] + p[3])) + ((p[4] + p[5]) + (p[6] + p[7]));
        lsB += ((p[8] + p[9]) + (p[10] + p[11])) + ((p[12] + p[13]) + (p[14] + p[15]));

        union { unsigned int u[8]; short8 v[2]; } pb;
        #pragma unroll
        for (int jj = 0; jj < 8; ++jj)
          asm("v_cvt_pk_bf16_f32 %0, %1, %2"
              : "=v"(pb.u[jj]) : "v"(p[2 * jj]), "v"(p[2 * jj + 1]));

        O = __builtin_amdgcn_mfma_f32_32x32x16_bf16(av0, pb.v[0], O, 0, 0, 0);
        O = __builtin_amdgcn_mfma_f32_32x32x16_bf16(av1, pb.v[1], O, 0, 0, 0);
      }
    }

    __syncthreads();                                  // drains vmcnt: DMA landed
  }

  float lsum = lsA + lsB;
  float ltot = lsum + __shfl_xor(lsum, 32);
  float linv = (ltot > 0.f) ? 1.f / ltot : 0.f;       // q==0 row -> all zeros
  int b = bh >> 3, h = bh & 7;
  float* ob = out + ((size_t)(b * 256 + h * 32)) * S_ + q0 + col;
  #pragma unroll
  for (int r = 0; r < 16; ++r) {
    int d = (r & 3) + 8 * (r >> 2) + 4 * hi;
    ob[(size_t)d * S_] = O[r] * linv;
  }
}

// ---------------------------------------------------------------------------
extern "C" void kernel_launch(void* const* d_in, const int* in_sizes, int n_in,
                              void* d_out, int out_size, void* d_ws, size_t ws_size,
                              hipStream_t stream) {
  const float* x   = (const float*)d_in[0];
  const float* qw  = (const float*)d_in[1];
  const float* qb  = (const float*)d_in[2];
  const float* kvw = (const float*)d_in[3];
  const float* kvb = (const float*)d_in[4];
  float* out = (float*)d_out;

  char* ws = (char*)d_ws;
  unsigned short* wt   = (unsigned short*)(ws + 0);         //   768*256*2 = 393216
  float*          bias = (float*)(ws + 393216);             //   768*4     = 3072
  unsigned short* xt   = (unsigned short*)(ws + 396288);    //  32*1024*256*2
  unsigned short* qws  = (unsigned short*)(ws + 17173504);  //  32*8*1024*32*2
  unsigned short* kv   = (unsigned short*)(ws + 33950720);  //  256*32*2048*2 = 33554432
                                                            //  ends at 67505152

  k_prep<<<8960, 256, 0, stream>>>(x, xt, qw, qb, kvw, kvb, wt, bias);
  k_proj<<<dim3(48, 32), 512, 0, stream>>>(wt, bias, xt, qws, kv);
  k_attn<<<1024, 512, 0, stream>>>(qws, kv, out);
}